// Round 6
// baseline (1575.815 us; speedup 1.0000x reference)
//
#include <hip/hip_runtime.h>
#include <math.h>

#define B 2048
#define C 1024

typedef _Float16 v2h __attribute__((ext_vector_type(2)));

// ---------------------------------------------------------------------------
// Kernel 1: row softmax of y/2 for both inputs -> fp16 output.
// ---------------------------------------------------------------------------
__global__ __launch_bounds__(256) void softmax_k(const float* __restrict__ ys,
                                                 const float* __restrict__ yt,
                                                 _Float16* __restrict__ ps,
                                                 _Float16* __restrict__ pt) {
    int b = blockIdx.x;
    const float* in;
    _Float16* out;
    if (b < B) { in = ys + (size_t)b * C;        out = ps + (size_t)b * C; }
    else       { in = yt + (size_t)(b - B) * C;  out = pt + (size_t)(b - B) * C; }
    int tid = threadIdx.x;
    int lane = tid & 63, wave = tid >> 6;

    float4 v = reinterpret_cast<const float4*>(in)[tid];
    v.x *= 0.5f; v.y *= 0.5f; v.z *= 0.5f; v.w *= 0.5f;

    float mx = fmaxf(fmaxf(v.x, v.y), fmaxf(v.z, v.w));
    #pragma unroll
    for (int m = 32; m >= 1; m >>= 1) mx = fmaxf(mx, __shfl_xor(mx, m, 64));
    __shared__ float redm[4];
    if (lane == 0) redm[wave] = mx;
    __syncthreads();
    mx = fmaxf(fmaxf(redm[0], redm[1]), fmaxf(redm[2], redm[3]));

    float4 e;
    e.x = expf(v.x - mx); e.y = expf(v.y - mx);
    e.z = expf(v.z - mx); e.w = expf(v.w - mx);
    float s = e.x + e.y + e.z + e.w;
    #pragma unroll
    for (int m = 32; m >= 1; m >>= 1) s += __shfl_xor(s, m, 64);
    __shared__ float reds[4];
    if (lane == 0) reds[wave] = s;
    __syncthreads();
    s = reds[0] + reds[1] + reds[2] + reds[3];

    float inv = 1.0f / s;
    float2 st;
    v2h* sp = (v2h*)&st;
    sp[0] = (v2h){(_Float16)(e.x * inv), (_Float16)(e.y * inv)};
    sp[1] = (v2h){(_Float16)(e.z * inv), (_Float16)(e.w * inv)};
    reinterpret_cast<float2*>(out)[tid] = st;
}

// ---------------------------------------------------------------------------
// Kernel 2: K[i][j] = exp(20*S - 20) stored fp16, S = sum_c min(ps,pt).
// 64x64 tile, 1024 blocks, 4x4/thread. Inner: v_pk_min_f16 + v_pk_add_f16
// into v2h accumulators, flushed to fp32 once per 32-half chunk.
// ---------------------------------------------------------------------------
__global__ __launch_bounds__(256) void cdist_k(const _Float16* __restrict__ ps,
                                               const _Float16* __restrict__ pt,
                                               _Float16* __restrict__ Km) {
    __shared__ __align__(16) v2h As[16][66];
    __shared__ __align__(16) v2h Bs[16][66];
    int tid = threadIdx.x;
    int tx = tid & 15, ty = tid >> 4;
    int r0 = blockIdx.y * 64, c0 = blockIdx.x * 64;

    float acc[4][4];
    #pragma unroll
    for (int i = 0; i < 4; ++i)
        #pragma unroll
        for (int j = 0; j < 4; ++j) acc[i][j] = 0.f;

    int lr = tid >> 2;
    int lq = tid & 3;
    const float4* pa = reinterpret_cast<const float4*>(ps + (size_t)(r0 + lr) * C);
    const float4* pb = reinterpret_cast<const float4*>(pt + (size_t)(c0 + lr) * C);

    for (int ch = 0; ch < 32; ++ch) {
        float4 a0 = pa[ch * 4 + lq];
        float4 b0 = pb[ch * 4 + lq];
        v2h* ah = (v2h*)&a0;
        v2h* bh = (v2h*)&b0;
        #pragma unroll
        for (int c2 = 0; c2 < 4; ++c2) {
            As[lq * 4 + c2][lr] = ah[c2];
            Bs[lq * 4 + c2][lr] = bh[c2];
        }
        __syncthreads();
        v2h macc[4][4];
        #pragma unroll
        for (int k2 = 0; k2 < 16; ++k2) {
            v2h a2[4], b2[4];
            *(float4*)&a2[0] = *(const float4*)&As[k2][ty * 4];
            *(float4*)&b2[0] = *(const float4*)&Bs[k2][tx * 4];
            #pragma unroll
            for (int i = 0; i < 4; ++i)
                #pragma unroll
                for (int j = 0; j < 4; ++j) {
                    v2h m = __builtin_elementwise_min(a2[i], b2[j]);
                    if (k2 == 0) macc[i][j] = m;
                    else         macc[i][j] = macc[i][j] + m;   // v_pk_add_f16
                }
        }
        #pragma unroll
        for (int i = 0; i < 4; ++i)
            #pragma unroll
            for (int j = 0; j < 4; ++j)
                acc[i][j] += (float)macc[i][j].x + (float)macc[i][j].y;
        __syncthreads();
    }

    #pragma unroll
    for (int i = 0; i < 4; ++i) {
        int row = r0 + ty * 4 + i;
        float k0 = __expf(20.f * acc[i][0] - 20.f);
        float k1 = __expf(20.f * acc[i][1] - 20.f);
        float k2 = __expf(20.f * acc[i][2] - 20.f);
        float k3 = __expf(20.f * acc[i][3] - 20.f);
        float2 st;
        v2h* hp = (v2h*)&st;
        hp[0] = (v2h){(_Float16)k0, (_Float16)k1};
        hp[1] = (v2h){(_Float16)k2, (_Float16)k3};
        *reinterpret_cast<float2*>(&Km[(size_t)row * B + c0 + tx * 4]) = st;
    }
}

// ---------------------------------------------------------------------------
// Grid barrier (proven in R3): one arrival atomic per block, thread-0 spin.
// ---------------------------------------------------------------------------
__device__ __forceinline__ void gbar(int* ctr) {
    __syncthreads();
    if (threadIdx.x == 0) {
        __hip_atomic_fetch_add(ctr, 1, __ATOMIC_ACQ_REL, __HIP_MEMORY_SCOPE_AGENT);
        while (__hip_atomic_load(ctr, __ATOMIC_RELAXED, __HIP_MEMORY_SCOPE_AGENT) < 256)
            __builtin_amdgcn_s_sleep(2);
    }
    __threadfence();
    __syncthreads();
}

// ---------------------------------------------------------------------------
// Persistent Sinkhorn + loss. 256 blocks x 1024 threads (16 waves/CU, half
// capacity -> co-residency guaranteed). Block owns 8 rows; thread owns 2
// rotated columns; K slice lives in fp32 registers for all 20 iterations.
// Per iter: row-dot reduce -> a; col partials -> 2 rotated atomicAdds;
// grid barrier; reload 2 col sums. Loss fused at the end.
// ---------------------------------------------------------------------------
__global__ __launch_bounds__(1024, 4) void sink_k(const _Float16* __restrict__ Km,
                                                  float* __restrict__ svec,
                                                  float* __restrict__ out,
                                                  int* __restrict__ bar) {
    __shared__ float part[8][16];
    __shared__ float a_lds[8];
    int t = threadIdx.x;
    int lane = t & 63, wv = t >> 6;
    int bid = blockIdx.x;
    int r0 = bid * 8;
    int jx = (2 * t + 8 * bid) & (B - 1);

    float kx[8], ky[8];
    #pragma unroll
    for (int i = 0; i < 8; ++i) {
        v2h k2 = *reinterpret_cast<const v2h*>(&Km[(size_t)(r0 + i) * B + jx]);
        kx[i] = (float)k2.x;
        ky[i] = (float)k2.y;
    }

    float bx = 1.0f, by = 1.0f;    // b_0 = 1 (svec[0] never materialized)

    for (int it = 1; it <= 20; ++it) {
        // row pass: partial dots for this block's 8 rows
        #pragma unroll
        for (int i = 0; i < 8; ++i) {
            float v = kx[i] * bx + ky[i] * by;
            #pragma unroll
            for (int m = 32; m >= 1; m >>= 1) v += __shfl_xor(v, m, 64);
            if (lane == 0) part[i][wv] = v;
        }
        __syncthreads();
        if (t < 8) {
            float s = 0.f;
            #pragma unroll
            for (int w = 0; w < 16; ++w) s += part[t][w];
            a_lds[t] = 1.0f / s;
        }
        __syncthreads();

        // col pass: this block's contribution to the 2 owned columns
        float cx = 0.f, cy = 0.f;
        #pragma unroll
        for (int i = 0; i < 8; ++i) {
            float ai = a_lds[i];
            cx += ai * kx[i];
            cy += ai * ky[i];
        }
        float* sn = svec + (size_t)it * B;
        atomicAdd(&sn[jx], cx);
        atomicAdd(&sn[jx + 1], cy);

        gbar(&bar[it]);

        bx = 1.0f / __hip_atomic_load(&sn[jx], __ATOMIC_RELAXED,
                                      __HIP_MEMORY_SCOPE_AGENT);
        by = 1.0f / __hip_atomic_load(&sn[jx + 1], __ATOMIC_RELAXED,
                                      __HIP_MEMORY_SCOPE_AGENT);
    }

    // loss: bx,by now hold 1/svec[20] for the owned columns; a_lds holds a.
    float acc = 0.f;
    #pragma unroll
    for (int i = 0; i < 8; ++i) {
        float ai = a_lds[i];
        acc += ai * (kx[i] * bx * __logf(fmaxf(kx[i], 1e-20f))
                   + ky[i] * by * __logf(fmaxf(ky[i], 1e-20f)));
    }
    #pragma unroll
    for (int m = 32; m >= 1; m >>= 1) acc += __shfl_xor(acc, m, 64);
    if (lane == 0) part[0][wv] = acc;
    __syncthreads();
    if (t == 0) {
        float s = 0.f;
        #pragma unroll
        for (int w = 0; w < 16; ++w) s += part[0][w];
        atomicAdd(out, -0.1f * 0.001f * s);
    }
}

// ---------------------------------------------------------------------------
extern "C" void kernel_launch(void* const* d_in, const int* in_sizes, int n_in,
                              void* d_out, int out_size, void* d_ws, size_t ws_size,
                              hipStream_t stream) {
    const float* ys = (const float*)d_in[0];
    const float* yt = (const float*)d_in[1];
    float* out = (float*)d_out;

    char* wsb = (char*)d_ws;
    _Float16* ps = (_Float16*)wsb;                               // 4 MB
    _Float16* pt = (_Float16*)(wsb + (size_t)B * C * 2);         // 4 MB
    _Float16* Km = (_Float16*)(wsb + (size_t)2 * B * C * 2);     // 8.4 MB
    float* svec  = (float*)(wsb + (size_t)2 * B * C * 2 + (size_t)B * B * 2);
    int*   bar   = (int*)(svec + (size_t)21 * B);                // 32 ints

    // zero: svec slices 1..20, barrier counters, out
    (void)hipMemsetAsync(svec + B, 0,
                         (size_t)20 * B * sizeof(float) + 32 * sizeof(int), stream);
    (void)hipMemsetAsync(out, 0, sizeof(float), stream);

    softmax_k<<<2 * B, 256, 0, stream>>>(ys, yt, ps, pt);
    cdist_k<<<dim3(32, 32), 256, 0, stream>>>(ps, pt, Km);
    sink_k<<<256, 1024, 0, stream>>>(Km, svec, out, bar);
}

// Round 7
// 702.237 us; speedup vs baseline: 2.2440x; 2.2440x over previous
//
#include <hip/hip_runtime.h>
#include <math.h>

#define B 2048
#define C 1024

typedef _Float16 v2h __attribute__((ext_vector_type(2)));

// ---------------------------------------------------------------------------
// Kernel 1: row softmax of y/2 for both inputs -> fp16 output.
// ---------------------------------------------------------------------------
__global__ __launch_bounds__(256) void softmax_k(const float* __restrict__ ys,
                                                 const float* __restrict__ yt,
                                                 _Float16* __restrict__ ps,
                                                 _Float16* __restrict__ pt) {
    int b = blockIdx.x;
    const float* in;
    _Float16* out;
    if (b < B) { in = ys + (size_t)b * C;        out = ps + (size_t)b * C; }
    else       { in = yt + (size_t)(b - B) * C;  out = pt + (size_t)(b - B) * C; }
    int tid = threadIdx.x;
    int lane = tid & 63, wave = tid >> 6;

    float4 v = reinterpret_cast<const float4*>(in)[tid];
    v.x *= 0.5f; v.y *= 0.5f; v.z *= 0.5f; v.w *= 0.5f;

    float mx = fmaxf(fmaxf(v.x, v.y), fmaxf(v.z, v.w));
    #pragma unroll
    for (int m = 32; m >= 1; m >>= 1) mx = fmaxf(mx, __shfl_xor(mx, m, 64));
    __shared__ float redm[4];
    if (lane == 0) redm[wave] = mx;
    __syncthreads();
    mx = fmaxf(fmaxf(redm[0], redm[1]), fmaxf(redm[2], redm[3]));

    float4 e;
    e.x = expf(v.x - mx); e.y = expf(v.y - mx);
    e.z = expf(v.z - mx); e.w = expf(v.w - mx);
    float s = e.x + e.y + e.z + e.w;
    #pragma unroll
    for (int m = 32; m >= 1; m >>= 1) s += __shfl_xor(s, m, 64);
    __shared__ float reds[4];
    if (lane == 0) reds[wave] = s;
    __syncthreads();
    s = reds[0] + reds[1] + reds[2] + reds[3];

    float inv = 1.0f / s;
    float2 st;
    v2h* sp = (v2h*)&st;
    sp[0] = (v2h){(_Float16)(e.x * inv), (_Float16)(e.y * inv)};
    sp[1] = (v2h){(_Float16)(e.z * inv), (_Float16)(e.w * inv)};
    reinterpret_cast<float2*>(out)[tid] = st;
}

// ---------------------------------------------------------------------------
// Kernel 2: K = exp(20*S - 20) stored fp16 to BOTH Km and KmT (transposed).
// 64x64 tile, 4x4/thread, pk_min + pk_add fp16 chunk accumulation (R5-proven).
// ---------------------------------------------------------------------------
__global__ __launch_bounds__(256) void cdist_k(const _Float16* __restrict__ ps,
                                               const _Float16* __restrict__ pt,
                                               _Float16* __restrict__ Km,
                                               _Float16* __restrict__ KmT) {
    __shared__ __align__(16) v2h As[16][66];
    __shared__ __align__(16) v2h Bs[16][66];
    int tid = threadIdx.x;
    int tx = tid & 15, ty = tid >> 4;
    int r0 = blockIdx.y * 64, c0 = blockIdx.x * 64;

    float acc[4][4];
    #pragma unroll
    for (int i = 0; i < 4; ++i)
        #pragma unroll
        for (int j = 0; j < 4; ++j) acc[i][j] = 0.f;

    int lr = tid >> 2;
    int lq = tid & 3;
    const float4* pa = reinterpret_cast<const float4*>(ps + (size_t)(r0 + lr) * C);
    const float4* pb = reinterpret_cast<const float4*>(pt + (size_t)(c0 + lr) * C);

    for (int ch = 0; ch < 32; ++ch) {
        float4 a0 = pa[ch * 4 + lq];
        float4 b0 = pb[ch * 4 + lq];
        v2h* ah = (v2h*)&a0;
        v2h* bh = (v2h*)&b0;
        #pragma unroll
        for (int c2 = 0; c2 < 4; ++c2) {
            As[lq * 4 + c2][lr] = ah[c2];
            Bs[lq * 4 + c2][lr] = bh[c2];
        }
        __syncthreads();
        v2h macc[4][4];
        #pragma unroll
        for (int k2 = 0; k2 < 16; ++k2) {
            v2h a2[4], b2[4];
            *(float4*)&a2[0] = *(const float4*)&As[k2][ty * 4];
            *(float4*)&b2[0] = *(const float4*)&Bs[k2][tx * 4];
            #pragma unroll
            for (int i = 0; i < 4; ++i)
                #pragma unroll
                for (int j = 0; j < 4; ++j) {
                    v2h m = __builtin_elementwise_min(a2[i], b2[j]);
                    if (k2 == 0) macc[i][j] = m;
                    else         macc[i][j] = macc[i][j] + m;
                }
        }
        #pragma unroll
        for (int i = 0; i < 4; ++i)
            #pragma unroll
            for (int j = 0; j < 4; ++j)
                acc[i][j] += (float)macc[i][j].x + (float)macc[i][j].y;
        __syncthreads();
    }

    float ke[4][4];
    #pragma unroll
    for (int i = 0; i < 4; ++i)
        #pragma unroll
        for (int j = 0; j < 4; ++j)
            ke[i][j] = __expf(20.f * acc[i][j] - 20.f);

    // K store: row-major, 8B per thread-row
    #pragma unroll
    for (int i = 0; i < 4; ++i) {
        float2 st;
        v2h* hp = (v2h*)&st;
        hp[0] = (v2h){(_Float16)ke[i][0], (_Float16)ke[i][1]};
        hp[1] = (v2h){(_Float16)ke[i][2], (_Float16)ke[i][3]};
        *reinterpret_cast<float2*>(&Km[(size_t)(r0 + ty * 4 + i) * B + c0 + tx * 4]) = st;
    }
    // KT store: KmT[col][row]
    #pragma unroll
    for (int j = 0; j < 4; ++j) {
        float2 st;
        v2h* hp = (v2h*)&st;
        hp[0] = (v2h){(_Float16)ke[0][j], (_Float16)ke[1][j]};
        hp[1] = (v2h){(_Float16)ke[2][j], (_Float16)ke[3][j]};
        *reinterpret_cast<float2*>(&KmT[(size_t)(c0 + tx * 4 + j) * B + r0 + ty * 4]) = st;
    }
}

// ---------------------------------------------------------------------------
// Grid barrier: monotonic counter, release arrival (L2 writeback), relaxed
// spin, one acquire load on exit (L1+L2 invalidate). No per-element far ops.
// ---------------------------------------------------------------------------
__device__ __forceinline__ void gbar(int* ctr, int tgt) {
    __syncthreads();
    if (threadIdx.x == 0) {
        __hip_atomic_fetch_add(ctr, 1, __ATOMIC_RELEASE, __HIP_MEMORY_SCOPE_AGENT);
        while (__hip_atomic_load(ctr, __ATOMIC_RELAXED, __HIP_MEMORY_SCOPE_AGENT) < tgt)
            __builtin_amdgcn_s_sleep(4);
        (void)__hip_atomic_load(ctr, __ATOMIC_ACQUIRE, __HIP_MEMORY_SCOPE_AGENT);
    }
    __syncthreads();
}

// ---------------------------------------------------------------------------
// Persistent Sinkhorn + loss, ZERO atomics in the loop. 256 blocks x 1024 thr.
// Thread holds K[r0..r0+7][2t..2t+1] and KT[r0..r0+7][2t..2t+1] in registers.
// Row pass -> 8 plain stores of a; barrier; col pass (via KT) -> 8 plain
// stores of s; barrier. Vectors read via plain cached loads (valid after
// acquire-invalidate). Loss fused at the end.
// ---------------------------------------------------------------------------
__global__ __launch_bounds__(1024) void sink3_k(const _Float16* __restrict__ Km,
                                                const _Float16* __restrict__ KmT,
                                                float* __restrict__ svec,
                                                float* __restrict__ avec,
                                                float* __restrict__ out,
                                                int* __restrict__ ctr) {
    __shared__ float part[8][16];
    __shared__ float a_lds[8];
    int t = threadIdx.x;
    int lane = t & 63, wv = t >> 6;
    int bid = blockIdx.x;
    int r0 = bid * 8;
    int jx = 2 * t;

    v2h kA[8], kT[8];
    #pragma unroll
    for (int i = 0; i < 8; ++i) {
        kA[i] = *reinterpret_cast<const v2h*>(&Km[(size_t)(r0 + i) * B + jx]);
        kT[i] = *reinterpret_cast<const v2h*>(&KmT[(size_t)(r0 + i) * B + jx]);
    }
    float kAx[8], kAy[8], kTx[8], kTy[8];
    #pragma unroll
    for (int i = 0; i < 8; ++i) {
        kAx[i] = (float)kA[i].x; kAy[i] = (float)kA[i].y;
        kTx[i] = (float)kT[i].x; kTy[i] = (float)kT[i].y;
    }

    float bx = 1.0f, by = 1.0f;     // b_0 = 1
    int tgt = 0;

    for (int it = 0; it < 20; ++it) {
        // ---- row pass: a_i = 1 / sum_j K_ij * b_j ----
        #pragma unroll
        for (int i = 0; i < 8; ++i) {
            float v = kAx[i] * bx + kAy[i] * by;
            #pragma unroll
            for (int m = 32; m >= 1; m >>= 1) v += __shfl_xor(v, m, 64);
            if (lane == 0) part[i][wv] = v;
        }
        __syncthreads();
        if (t < 8) {
            float s = 0.f;
            #pragma unroll
            for (int w = 0; w < 16; ++w) s += part[t][w];
            float av = 1.0f / s;
            a_lds[t] = av;
            avec[r0 + t] = av;
        }
        tgt += 256;
        gbar(ctr, tgt);

        // ---- col pass: s_j = sum_i a_i K_ij  (rows of KT) ----
        float2 av2 = *reinterpret_cast<const float2*>(&avec[jx]);
        #pragma unroll
        for (int i = 0; i < 8; ++i) {
            float v = kTx[i] * av2.x + kTy[i] * av2.y;
            #pragma unroll
            for (int m = 32; m >= 1; m >>= 1) v += __shfl_xor(v, m, 64);
            if (lane == 0) part[i][wv] = v;
        }
        __syncthreads();
        if (t < 8) {
            float s = 0.f;
            #pragma unroll
            for (int w = 0; w < 16; ++w) s += part[t][w];
            svec[r0 + t] = s;
        }
        tgt += 256;
        gbar(ctr, tgt);

        if (it < 19) {
            float2 sv = *reinterpret_cast<const float2*>(&svec[jx]);
            bx = 1.0f / sv.x;
            by = 1.0f / sv.y;
        }
    }

    // ---- loss: 0.001 * sum_ij a_i K_ij (1/s20_j) * (-0.1 ln K_ij) ----
    float2 sv = *reinterpret_cast<const float2*>(&svec[jx]);
    float ibx = 1.0f / sv.x, iby = 1.0f / sv.y;
    float acc = 0.f;
    #pragma unroll
    for (int i = 0; i < 8; ++i) {
        float ai = a_lds[i];
        acc += ai * (kAx[i] * ibx * __logf(fmaxf(kAx[i], 1e-20f))
                   + kAy[i] * iby * __logf(fmaxf(kAy[i], 1e-20f)));
    }
    #pragma unroll
    for (int m = 32; m >= 1; m >>= 1) acc += __shfl_xor(acc, m, 64);
    if (lane == 0) part[0][wv] = acc;
    __syncthreads();
    if (t == 0) {
        float s = 0.f;
        #pragma unroll
        for (int w = 0; w < 16; ++w) s += part[0][w];
        atomicAdd(out, -0.1f * 0.001f * s);
    }
}

// ---------------------------------------------------------------------------
extern "C" void kernel_launch(void* const* d_in, const int* in_sizes, int n_in,
                              void* d_out, int out_size, void* d_ws, size_t ws_size,
                              hipStream_t stream) {
    const float* ys = (const float*)d_in[0];
    const float* yt = (const float*)d_in[1];
    float* out = (float*)d_out;

    char* wsb = (char*)d_ws;
    _Float16* ps  = (_Float16*)wsb;                                  // 4 MB
    _Float16* pt  = (_Float16*)(wsb + (size_t)B * C * 2);            // 4 MB
    _Float16* Km  = (_Float16*)(wsb + (size_t)2 * B * C * 2);        // 8.4 MB
    _Float16* KmT = Km + (size_t)B * B;                              // 8.4 MB
    float* svec   = (float*)(KmT + (size_t)B * B);                   // 8 KB
    float* avec   = svec + B;                                        // 8 KB
    int*   ctr    = (int*)(avec + B);

    (void)hipMemsetAsync(ctr, 0, sizeof(int), stream);
    (void)hipMemsetAsync(out, 0, sizeof(float), stream);

    softmax_k<<<2 * B, 256, 0, stream>>>(ys, yt, ps, pt);
    cdist_k<<<dim3(32, 32), 256, 0, stream>>>(ps, pt, Km, KmT);
    sink3_k<<<256, 1024, 0, stream>>>(Km, KmT, svec, avec, out, ctr);
}

// Round 9
// 607.118 us; speedup vs baseline: 2.5956x; 1.1567x over previous
//
#include <hip/hip_runtime.h>
#include <hip/hip_fp16.h>
#include <math.h>

#define B 2048
#define C 1024

typedef _Float16 v2h __attribute__((ext_vector_type(2)));

// ---------------------------------------------------------------------------
// Kernel 1: row softmax of y/2 for both inputs -> fp16 output.
// ---------------------------------------------------------------------------
__global__ __launch_bounds__(256) void softmax_k(const float* __restrict__ ys,
                                                 const float* __restrict__ yt,
                                                 _Float16* __restrict__ ps,
                                                 _Float16* __restrict__ pt) {
    int b = blockIdx.x;
    const float* in;
    _Float16* out;
    if (b < B) { in = ys + (size_t)b * C;        out = ps + (size_t)b * C; }
    else       { in = yt + (size_t)(b - B) * C;  out = pt + (size_t)(b - B) * C; }
    int tid = threadIdx.x;
    int lane = tid & 63, wave = tid >> 6;

    float4 v = reinterpret_cast<const float4*>(in)[tid];
    v.x *= 0.5f; v.y *= 0.5f; v.z *= 0.5f; v.w *= 0.5f;

    float mx = fmaxf(fmaxf(v.x, v.y), fmaxf(v.z, v.w));
    #pragma unroll
    for (int m = 32; m >= 1; m >>= 1) mx = fmaxf(mx, __shfl_xor(mx, m, 64));
    __shared__ float redm[4];
    if (lane == 0) redm[wave] = mx;
    __syncthreads();
    mx = fmaxf(fmaxf(redm[0], redm[1]), fmaxf(redm[2], redm[3]));

    float4 e;
    e.x = expf(v.x - mx); e.y = expf(v.y - mx);
    e.z = expf(v.z - mx); e.w = expf(v.w - mx);
    float s = e.x + e.y + e.z + e.w;
    #pragma unroll
    for (int m = 32; m >= 1; m >>= 1) s += __shfl_xor(s, m, 64);
    __shared__ float reds[4];
    if (lane == 0) reds[wave] = s;
    __syncthreads();
    s = reds[0] + reds[1] + reds[2] + reds[3];

    float inv = 1.0f / s;
    float2 st;
    v2h* sp = (v2h*)&st;
    sp[0] = (v2h){(_Float16)(e.x * inv), (_Float16)(e.y * inv)};
    sp[1] = (v2h){(_Float16)(e.z * inv), (_Float16)(e.w * inv)};
    reinterpret_cast<float2*>(out)[tid] = st;
}

// ---------------------------------------------------------------------------
// Kernel 2: K = exp(20*S - 20) fp16 to BOTH Km and KmT. 64x64 tile,
// 4x4/thread. Inner loop: guaranteed packed v_pk_min_f16 + v_pk_add_f16 via
// inline asm on uint-packed half2 operands; fp16 chunk accumulator flushed
// to fp32 every 32 halfs.
// ---------------------------------------------------------------------------
__global__ __launch_bounds__(256) void cdist_k(const _Float16* __restrict__ ps,
                                               const _Float16* __restrict__ pt,
                                               _Float16* __restrict__ Km,
                                               _Float16* __restrict__ KmT) {
    __shared__ __align__(16) unsigned int As[16][66];
    __shared__ __align__(16) unsigned int Bs[16][66];
    int tid = threadIdx.x;
    int tx = tid & 15, ty = tid >> 4;
    int r0 = blockIdx.y * 64, c0 = blockIdx.x * 64;

    float acc[4][4];
    #pragma unroll
    for (int i = 0; i < 4; ++i)
        #pragma unroll
        for (int j = 0; j < 4; ++j) acc[i][j] = 0.f;

    int lr = tid >> 2;
    int lq = tid & 3;
    const uint4* pa = reinterpret_cast<const uint4*>(ps + (size_t)(r0 + lr) * C);
    const uint4* pb = reinterpret_cast<const uint4*>(pt + (size_t)(c0 + lr) * C);

    for (int ch = 0; ch < 32; ++ch) {
        uint4 a0 = pa[ch * 4 + lq];
        uint4 b0 = pb[ch * 4 + lq];
        unsigned int* ah = (unsigned int*)&a0;
        unsigned int* bh = (unsigned int*)&b0;
        #pragma unroll
        for (int c2 = 0; c2 < 4; ++c2) {
            As[lq * 4 + c2][lr] = ah[c2];
            Bs[lq * 4 + c2][lr] = bh[c2];
        }
        __syncthreads();
        unsigned int macc[4][4];
        #pragma unroll
        for (int k2 = 0; k2 < 16; ++k2) {
            unsigned int a2[4], b2[4];
            *(uint4*)&a2[0] = *(const uint4*)&As[k2][ty * 4];
            *(uint4*)&b2[0] = *(const uint4*)&Bs[k2][tx * 4];
            #pragma unroll
            for (int i = 0; i < 4; ++i)
                #pragma unroll
                for (int j = 0; j < 4; ++j) {
                    unsigned int m;
                    asm("v_pk_min_f16 %0, %1, %2" : "=v"(m) : "v"(a2[i]), "v"(b2[j]));
                    if (k2 == 0) macc[i][j] = m;
                    else asm("v_pk_add_f16 %0, %1, %2"
                             : "=v"(macc[i][j]) : "v"(macc[i][j]), "v"(m));
                }
        }
        #pragma unroll
        for (int i = 0; i < 4; ++i)
            #pragma unroll
            for (int j = 0; j < 4; ++j) {
                v2h h = __builtin_bit_cast(v2h, macc[i][j]);
                acc[i][j] += (float)h.x + (float)h.y;
            }
        __syncthreads();
    }

    float ke[4][4];
    #pragma unroll
    for (int i = 0; i < 4; ++i)
        #pragma unroll
        for (int j = 0; j < 4; ++j)
            ke[i][j] = __expf(20.f * acc[i][j] - 20.f);

    #pragma unroll
    for (int i = 0; i < 4; ++i) {
        float2 st;
        v2h* hp = (v2h*)&st;
        hp[0] = (v2h){(_Float16)ke[i][0], (_Float16)ke[i][1]};
        hp[1] = (v2h){(_Float16)ke[i][2], (_Float16)ke[i][3]};
        *reinterpret_cast<float2*>(&Km[(size_t)(r0 + ty * 4 + i) * B + c0 + tx * 4]) = st;
    }
    #pragma unroll
    for (int j = 0; j < 4; ++j) {
        float2 st;
        v2h* hp = (v2h*)&st;
        hp[0] = (v2h){(_Float16)ke[0][j], (_Float16)ke[1][j]};
        hp[1] = (v2h){(_Float16)ke[2][j], (_Float16)ke[3][j]};
        *reinterpret_cast<float2*>(&KmT[(size_t)(c0 + tx * 4 + j) * B + r0 + ty * 4]) = st;
    }
}

// ---------------------------------------------------------------------------
// Hierarchical grid barrier: 16 group counters (16 blocks each, 256B apart)
// -> root -> per-group go flags. ~32 serialized RMWs instead of 256.
// Monotonic epochs, no reset. Final observed load is ACQUIRE (L1/L2 inv).
// ---------------------------------------------------------------------------
__device__ __forceinline__ void gbar(int* bar, int ep) {
    __syncthreads();
    if (threadIdx.x == 0) {
        int bid = blockIdx.x;
        int g = bid >> 4;
        int* grp  = bar + g * 64;
        int* root = bar + 16 * 64;
        int* go   = bar + (17 + g) * 64;
        __hip_atomic_fetch_add(grp, 1, __ATOMIC_RELEASE, __HIP_MEMORY_SCOPE_AGENT);
        if ((bid & 15) == 0) {
            while (__hip_atomic_load(grp, __ATOMIC_RELAXED, __HIP_MEMORY_SCOPE_AGENT) < 16 * ep)
                __builtin_amdgcn_s_sleep(1);
            (void)__hip_atomic_load(grp, __ATOMIC_ACQUIRE, __HIP_MEMORY_SCOPE_AGENT);
            __hip_atomic_fetch_add(root, 1, __ATOMIC_RELEASE, __HIP_MEMORY_SCOPE_AGENT);
            while (__hip_atomic_load(root, __ATOMIC_RELAXED, __HIP_MEMORY_SCOPE_AGENT) < 16 * ep)
                __builtin_amdgcn_s_sleep(1);
            (void)__hip_atomic_load(root, __ATOMIC_ACQUIRE, __HIP_MEMORY_SCOPE_AGENT);
            __hip_atomic_store(go, ep, __ATOMIC_RELEASE, __HIP_MEMORY_SCOPE_AGENT);
        } else {
            while (__hip_atomic_load(go, __ATOMIC_RELAXED, __HIP_MEMORY_SCOPE_AGENT) < ep)
                __builtin_amdgcn_s_sleep(1);
            (void)__hip_atomic_load(go, __ATOMIC_ACQUIRE, __HIP_MEMORY_SCOPE_AGENT);
        }
    }
    __syncthreads();
}

// ---------------------------------------------------------------------------
// Persistent Sinkhorn + loss. 256 blocks x 512 thr (8 waves). Wave w owns
// row r=bid*8+w of K AND row r of KT (= col r of K); 32 fp32 regs each,
// lane-strided. Per pass: 16 LDS float2 reads + 32 fma + 6 shfls. b/a
// vectors staged to LDS once per pass from global (plain cached loads after
// barrier acquire-invalidate — validated R7). Zero atomics in the loop.
// ---------------------------------------------------------------------------
__global__ __launch_bounds__(512) void sink4_k(const _Float16* __restrict__ Km,
                                               const _Float16* __restrict__ KmT,
                                               float* __restrict__ svec,
                                               float* __restrict__ avec,
                                               float* __restrict__ out,
                                               int* __restrict__ bar) {
    __shared__ float binv[B];
    __shared__ float a_lds[B];
    __shared__ float wred[8];
    int t = threadIdx.x;
    int lane = t & 63, wv = t >> 6;
    int bid = blockIdx.x;
    int r = bid * 8 + wv;

    const v2h* kr = (const v2h*)(Km  + (size_t)r * B);
    const v2h* kt = (const v2h*)(KmT + (size_t)r * B);
    float kA[32], kT[32];
    #pragma unroll
    for (int ch = 0; ch < 16; ++ch) {
        v2h h = kr[ch * 64 + lane];
        kA[2 * ch] = (float)h.x; kA[2 * ch + 1] = (float)h.y;
        v2h g = kt[ch * 64 + lane];
        kT[2 * ch] = (float)g.x; kT[2 * ch + 1] = (float)g.y;
    }

    #pragma unroll
    for (int q = 0; q < 4; ++q) binv[q * 512 + t] = 1.0f;   // b_0 = 1
    __syncthreads();

    const float2* bl2 = (const float2*)binv;
    const float2* al2 = (const float2*)a_lds;
    float a_r = 0.f;
    int ep = 0;

    for (int it = 0; it < 20; ++it) {
        // row pass: a_r = 1 / sum_j K[r][j] * b[j]
        float v = 0.f;
        #pragma unroll
        for (int ch = 0; ch < 16; ++ch) {
            float2 b2 = bl2[ch * 64 + lane];
            v += kA[2 * ch] * b2.x + kA[2 * ch + 1] * b2.y;
        }
        #pragma unroll
        for (int m = 32; m >= 1; m >>= 1) v += __shfl_xor(v, m, 64);
        a_r = 1.0f / v;
        if (lane == 0) avec[r] = a_r;
        gbar(bar, ++ep);

        // stage a into LDS
        *(float4*)(a_lds + 4 * t) = *(const float4*)(avec + 4 * t);
        __syncthreads();

        // col pass: s_r = sum_i KT[r][i] * a[i]
        float s = 0.f;
        #pragma unroll
        for (int ch = 0; ch < 16; ++ch) {
            float2 a2 = al2[ch * 64 + lane];
            s += kT[2 * ch] * a2.x + kT[2 * ch + 1] * a2.y;
        }
        #pragma unroll
        for (int m = 32; m >= 1; m >>= 1) s += __shfl_xor(s, m, 64);
        if (lane == 0) svec[r] = s;
        gbar(bar, ++ep);

        // stage binv = 1/s into LDS
        float4 sf = *(const float4*)(svec + 4 * t);
        float4 bf = {1.f / sf.x, 1.f / sf.y, 1.f / sf.z, 1.f / sf.w};
        *(float4*)(binv + 4 * t) = bf;
        __syncthreads();
    }

    // loss: 0.001 * sum_ij a_i K_ij b_j * (-0.1 ln K_ij); binv holds 1/s20
    float acc = 0.f;
    #pragma unroll
    for (int ch = 0; ch < 16; ++ch) {
        float2 b2 = bl2[ch * 64 + lane];
        float k0 = kA[2 * ch], k1 = kA[2 * ch + 1];
        acc += k0 * b2.x * __logf(fmaxf(k0, 1e-20f))
             + k1 * b2.y * __logf(fmaxf(k1, 1e-20f));
    }
    #pragma unroll
    for (int m = 32; m >= 1; m >>= 1) acc += __shfl_xor(acc, m, 64);
    if (lane == 0) wred[wv] = a_r * acc;
    __syncthreads();
    if (t == 0) {
        float ssum = 0.f;
        #pragma unroll
        for (int w = 0; w < 8; ++w) ssum += wred[w];
        atomicAdd(out, -0.1f * 0.001f * ssum);
    }
}

// ---------------------------------------------------------------------------
extern "C" void kernel_launch(void* const* d_in, const int* in_sizes, int n_in,
                              void* d_out, int out_size, void* d_ws, size_t ws_size,
                              hipStream_t stream) {
    const float* ys = (const float*)d_in[0];
    const float* yt = (const float*)d_in[1];
    float* out = (float*)d_out;

    char* wsb = (char*)d_ws;
    _Float16* ps  = (_Float16*)wsb;                                  // 4 MB
    _Float16* pt  = (_Float16*)(wsb + (size_t)B * C * 2);            // 4 MB
    _Float16* Km  = (_Float16*)(wsb + (size_t)2 * B * C * 2);        // 8 MB
    _Float16* KmT = Km + (size_t)B * B;                              // 8 MB
    float* svec   = (float*)(KmT + (size_t)B * B);                   // 8 KB
    float* avec   = svec + B;                                        // 8 KB
    int*   bar    = (int*)(avec + B);                                // 33*64 ints

    (void)hipMemsetAsync(bar, 0, 34 * 64 * sizeof(int), stream);
    (void)hipMemsetAsync(out, 0, sizeof(float), stream);

    softmax_k<<<2 * B, 256, 0, stream>>>(ys, yt, ps, pt);
    cdist_k<<<dim3(32, 32), 256, 0, stream>>>(ps, pt, Km, KmT);
    sink4_k<<<256, 512, 0, stream>>>(Km, KmT, svec, avec, out, bar);
}